// Round 2
// baseline (332.654 us; speedup 1.0000x reference)
//
#include <hip/hip_runtime.h>
#include <hip/hip_bf16.h>

typedef unsigned short u16;
typedef unsigned int u32;
typedef __attribute__((ext_vector_type(8))) short bf16x8;
typedef __attribute__((ext_vector_type(4))) float f32x4;

#define MFMA16(a, b, c) __builtin_amdgcn_mfma_f32_16x16x32_bf16((a), (b), (c), 0, 0, 0)

__device__ __forceinline__ float bf2f(u16 h) {
    u32 u = ((u32)h) << 16;
    float f;
    __builtin_memcpy(&f, &u, 4);
    return f;
}
__device__ __forceinline__ u16 f2bf(float f) {
    u32 u;
    __builtin_memcpy(&u, &f, 4);
    u32 r = (u + 0x7FFFu + ((u >> 16) & 1u)) >> 16;  // RNE
    return (u16)r;
}

__device__ __forceinline__ void gload16(const void* g, void* l) {
    __builtin_amdgcn_global_load_lds((const __attribute__((address_space(1))) u32*)g,
                                     (__attribute__((address_space(3))) u32*)l, 16, 0, 0);
}

// fp32 -> bf16 bulk convert; each thread handles 8 floats. n must be grid*256*8.
__global__ __launch_bounds__(256) void cvt_bf16(const float* __restrict__ in, u16* __restrict__ out) {
    size_t i = ((size_t)blockIdx.x * 256 + threadIdx.x) * 8;
    f32x4 a = *(const f32x4*)(in + i);
    f32x4 b = *(const f32x4*)(in + i + 4);
    union {
        bf16x8 v;
        u16 s[8];
    } r;
    r.s[0] = f2bf(a[0]);
    r.s[1] = f2bf(a[1]);
    r.s[2] = f2bf(a[2]);
    r.s[3] = f2bf(a[3]);
    r.s[4] = f2bf(b[0]);
    r.s[5] = f2bf(b[1]);
    r.s[6] = f2bf(b[2]);
    r.s[7] = f2bf(b[3]);
    *(bf16x8*)(out + i) = r.v;
}

// out[C][R] = bf16(in[R][C])^T, 64x64 LDS tiles (fp32 in, bf16 out)
__global__ __launch_bounds__(256) void transpose_f32_bf16(const float* __restrict__ in,
                                                          u16* __restrict__ out, int R, int C) {
    __shared__ u16 t[64][65];
    const int c0 = blockIdx.x * 64, r0 = blockIdx.y * 64;
    const int tid = threadIdx.x;
#pragma unroll
    for (int i = 0; i < 16; ++i) {
        int idx = i * 256 + tid;
        int r = idx >> 6, c = idx & 63;
        t[r][c] = f2bf(in[(size_t)(r0 + r) * C + c0 + c]);
    }
    __syncthreads();
#pragma unroll
    for (int i = 0; i < 16; ++i) {
        int idx = i * 256 + tid;
        int cc = idx >> 6, rr = idx & 63;
        out[(size_t)(c0 + cc) * R + r0 + rr] = t[rr][cc];
    }
}

// Stage a ROWS x 64-element bf16 tile into linear LDS (row = 128 bytes = 8 chunks
// of 16B). Source chunk index is XOR-swizzled by (row&7); readers XOR the
// 16B-chunk index with (row&7). global_load_lds dest = wave-uniform base + lane*16.
template <int ROWS>
__device__ __forceinline__ void stage_tile(const u16* gbase, int stride_e, u16* lds, int tid) {
    const int wbase16 = (tid & ~63) * 8;  // element offset of this wave's chunk base
#pragma unroll
    for (int i = 0; i < ROWS / 32; ++i) {
        int chunk = i * 256 + tid;
        int r = chunk >> 3;
        int c = chunk & 7;
        int sc = c ^ (r & 7);
        const u16* src = gbase + (size_t)r * stride_e + sc * 8;
        u16* dst = lds + i * 2048 + wbase16;
        gload16(src, dst);
    }
}

// C = A[M,K] * Bt[N,K]^T + bias (bias fp32).
// split=1 (QKV): cols<2048 -> Cb=[M][2048] bf16 (Q|K); cols>=2048 (V) -> vt[bh*64+dh][2048] bf16.
// split=0: Cf[M][Cstride] fp32.
__global__ __launch_bounds__(256) void gemm_bt(const u16* __restrict__ A, const u16* __restrict__ Bt,
                                               const float* __restrict__ bias, u16* __restrict__ Cb,
                                               u16* __restrict__ vt, float* __restrict__ Cf, int M,
                                               int N, int K, int Cstride, int split) {
    __shared__ __align__(16) u16 As[128 * 64];
    __shared__ __align__(16) u16 Bs[128 * 64];
    const int tid = threadIdx.x;
    const int lane = tid & 63, wid = tid >> 6;
    const int wr = wid >> 1, wc = wid & 1;
    const int g = lane >> 4, l15 = lane & 15;
    const int m0 = blockIdx.y * 128, n0 = blockIdx.x * 128;

    f32x4 acc[4][4] = {};

    for (int k0 = 0; k0 < K; k0 += 64) {
        __syncthreads();
        stage_tile<128>(A + (size_t)m0 * K + k0, K, As, tid);
        stage_tile<128>(Bt + (size_t)n0 * K + k0, K, Bs, tid);
        __syncthreads();
        bf16x8 af[4][2], bf[4][2];
#pragma unroll
        for (int m = 0; m < 4; ++m) {
            int row = wr * 64 + m * 16 + l15;
#pragma unroll
            for (int t = 0; t < 2; ++t) {
                int off = row * 128 + (((t * 4 + g) ^ (row & 7)) * 16);
                af[m][t] = *(const bf16x8*)((const char*)As + off);
            }
        }
#pragma unroll
        for (int n = 0; n < 4; ++n) {
            int row = wc * 64 + n * 16 + l15;
#pragma unroll
            for (int t = 0; t < 2; ++t) {
                int off = row * 128 + (((t * 4 + g) ^ (row & 7)) * 16);
                bf[n][t] = *(const bf16x8*)((const char*)Bs + off);
            }
        }
#pragma unroll
        for (int m = 0; m < 4; ++m)
#pragma unroll
            for (int n = 0; n < 4; ++n) {
                acc[m][n] = MFMA16(af[m][0], bf[n][0], acc[m][n]);
                acc[m][n] = MFMA16(af[m][1], bf[n][1], acc[m][n]);
            }
    }

#pragma unroll
    for (int m = 0; m < 4; ++m) {
        int row0 = m0 + wr * 64 + m * 16 + g * 4;  // C row = (lane>>4)*4 + reg
#pragma unroll
        for (int n = 0; n < 4; ++n) {
            int col = n0 + wc * 64 + n * 16 + l15;  // C col = lane&15
            float bs = bias ? bias[col] : 0.0f;
            if (!split) {
#pragma unroll
                for (int rr = 0; rr < 4; ++rr)
                    Cf[(size_t)(row0 + rr) * Cstride + col] = acc[m][n][rr] + bs;
            } else {
                if (col < 2048) {
#pragma unroll
                    for (int rr = 0; rr < 4; ++rr)
                        Cb[(size_t)(row0 + rr) * 2048 + col] = f2bf(acc[m][n][rr] + bs);
                } else {
                    int e2 = col - 2048;
                    int h = e2 >> 6, dh = e2 & 63;
                    int b = row0 >> 11, s = row0 & 2047;
                    u16 tmp[4];
#pragma unroll
                    for (int rr = 0; rr < 4; ++rr) tmp[rr] = f2bf(acc[m][n][rr] + bs);
                    u32 lo = (u32)tmp[0] | ((u32)tmp[1] << 16);
                    u32 hi = (u32)tmp[2] | ((u32)tmp[3] << 16);
                    u32* dst = (u32*)&vt[((size_t)((b * 16 + h) * 64 + dh)) * 2048 + s];
                    dst[0] = lo;
                    dst[1] = hi;
                }
            }
        }
    }
}

// Flash attention. qk = [8192][2048] bf16 (Q cols 0..1023 | K cols 1024..2047),
// vt = [64bh][64d][2048s] bf16. Block: (qtile, bh). 4 waves, each owns 16 q-rows.
__global__ __launch_bounds__(256) void attn_fwd(const u16* __restrict__ qk, const u16* __restrict__ vt,
                                                u16* __restrict__ out) {
    __shared__ __align__(16) u16 Ks[64 * 64];
    __shared__ __align__(16) u16 Vs[64 * 64];
    __shared__ __align__(16) u16 Ps[4][16 * 72];  // per-wave P, row stride 72 (pad for banks)
    const int tid = threadIdx.x;
    const int lane = tid & 63, w = tid >> 6;
    const int g = lane >> 4, l15 = lane & 15;
    const int bh = blockIdx.y, b = bh >> 4, h = bh & 15;
    const int q0 = blockIdx.x * 64 + w * 16;
    const size_t qrow = (size_t)b * 2048 + q0;

    bf16x8 qf[2];
#pragma unroll
    for (int t = 0; t < 2; ++t)
        qf[t] = *(const bf16x8*)&qk[(qrow + l15) * 2048 + h * 64 + t * 32 + g * 8];

    float m_r[4], l_r[4];
    f32x4 acc_o[4] = {};
#pragma unroll
    for (int r = 0; r < 4; ++r) {
        m_r[r] = -1e30f;
        l_r[r] = 0.f;
    }

    const u16* kbase = qk + (size_t)b * 2048 * 2048 + 1024 + h * 64;
    const u16* vbase = vt + (size_t)bh * 64 * 2048;

    for (int kv0 = 0; kv0 < 2048; kv0 += 64) {
        __syncthreads();
        stage_tile<64>(kbase + (size_t)kv0 * 2048, 2048, Ks, tid);
        stage_tile<64>(vbase + kv0, 2048, Vs, tid);
        __syncthreads();

        // S = Q K^T (C row = q, col = kv)
        float sv[4][4];
#pragma unroll
        for (int f = 0; f < 4; ++f) {
            int row = f * 16 + l15;
            int swz = row & 7;
            bf16x8 k0 = *(const bf16x8*)((const char*)Ks + row * 128 + ((g ^ swz) * 16));
            bf16x8 k1 = *(const bf16x8*)((const char*)Ks + row * 128 + (((4 + g) ^ swz) * 16));
            f32x4 s = {0.f, 0.f, 0.f, 0.f};
            s = MFMA16(qf[0], k0, s);
            s = MFMA16(qf[1], k1, s);
#pragma unroll
            for (int rr = 0; rr < 4; ++rr) sv[f][rr] = s[rr] * 0.125f;
        }

        // online softmax; each lane owns rows g*4+rr, cols f*16+l15
#pragma unroll
        for (int rr = 0; rr < 4; ++rr) {
            float mx = fmaxf(fmaxf(sv[0][rr], sv[1][rr]), fmaxf(sv[2][rr], sv[3][rr]));
#pragma unroll
            for (int off = 1; off < 16; off <<= 1) mx = fmaxf(mx, __shfl_xor(mx, off));
            float mn = fmaxf(m_r[rr], mx);
            float alpha = __expf(m_r[rr] - mn);
            m_r[rr] = mn;
            float rsum = 0.f;
#pragma unroll
            for (int f = 0; f < 4; ++f) {
                float p = __expf(sv[f][rr] - mn);
                Ps[w][(g * 4 + rr) * 72 + f * 16 + l15] = f2bf(p);
                rsum += p;
            }
#pragma unroll
            for (int off = 1; off < 16; off <<= 1) rsum += __shfl_xor(rsum, off);
            l_r[rr] = l_r[rr] * alpha + rsum;
#pragma unroll
            for (int fo = 0; fo < 4; ++fo) acc_o[fo][rr] *= alpha;
        }

        // PV: a = P (row=q=lane&15, elems kv), b = Vt (col=d, elems kv)
        bf16x8 pa[2];
#pragma unroll
        for (int t = 0; t < 2; ++t)
            pa[t] = *(const bf16x8*)&Ps[w][l15 * 72 + t * 32 + g * 8];

#pragma unroll
        for (int fo = 0; fo < 4; ++fo) {
            int row = fo * 16 + l15;
            int swz = row & 7;
            bf16x8 v0 = *(const bf16x8*)((const char*)Vs + row * 128 + ((g ^ swz) * 16));
            bf16x8 v1 = *(const bf16x8*)((const char*)Vs + row * 128 + (((4 + g) ^ swz) * 16));
            acc_o[fo] = MFMA16(pa[0], v0, acc_o[fo]);
            acc_o[fo] = MFMA16(pa[1], v1, acc_o[fo]);
        }
    }

#pragma unroll
    for (int fo = 0; fo < 4; ++fo) {
        int col = h * 64 + fo * 16 + l15;
#pragma unroll
        for (int rr = 0; rr < 4; ++rr) {
            out[(qrow + g * 4 + rr) * 1024 + col] = f2bf(acc_o[fo][rr] / l_r[rr]);
        }
    }
}

extern "C" void kernel_launch(void* const* d_in, const int* in_sizes, int n_in, void* d_out,
                              int out_size, void* d_ws, size_t ws_size, hipStream_t stream) {
    const float* x = (const float*)d_in[0];      // [4,2048,1024] fp32
    const float* w_qkv = (const float*)d_in[1];  // [1024,3072] fp32
    const float* b_qkv = (const float*)d_in[2];  // [3072] fp32
    const float* w_out = (const float*)d_in[3];  // [1024,1024] fp32
    const float* b_out = (const float*)d_in[4];  // [1024] fp32
    float* out = (float*)d_out;                  // [8192,1024] fp32

    u16* ws = (u16*)d_ws;
    u16* xbf = ws;                                // 8192*1024
    u16* WqkvT = xbf + (size_t)8192 * 1024;       // 3072*1024
    u16* WoutT = WqkvT + (size_t)3072 * 1024;     // 1024*1024
    u16* qkbuf = WoutT + (size_t)1024 * 1024;     // 8192*2048 (Q|K)
    u16* vtbuf = qkbuf + (size_t)8192 * 2048;     // 64*64*2048 (V transposed per head)
    u16* attnb = vtbuf + (size_t)64 * 64 * 2048;  // 8192*1024
    // total ws: 92,274,688 bytes

    cvt_bf16<<<4096, 256, 0, stream>>>(x, xbf);  // 4096*256*8 = 8388608 elements exact
    transpose_f32_bf16<<<dim3(48, 16), 256, 0, stream>>>(w_qkv, WqkvT, 1024, 3072);
    transpose_f32_bf16<<<dim3(16, 16), 256, 0, stream>>>(w_out, WoutT, 1024, 1024);

    // QKV projection: [8192,1024] x [1024,3072] + b_qkv -> qkbuf + vtbuf
    gemm_bt<<<dim3(24, 64), 256, 0, stream>>>(xbf, WqkvT, b_qkv, qkbuf, vtbuf, nullptr, 8192, 3072,
                                              1024, 2048, 1);

    // attention: grid (qtile=32, bh=64)
    attn_fwd<<<dim3(32, 64), 256, 0, stream>>>(qkbuf, vtbuf, attnb);

    // output projection: [8192,1024] x [1024,1024] + b_out -> d_out (fp32)
    gemm_bt<<<dim3(8, 64), 256, 0, stream>>>(attnb, WoutT, b_out, nullptr, nullptr, out, 8192, 1024,
                                             1024, 1024, 0);
}

// Round 3
// 254.560 us; speedup vs baseline: 1.3068x; 1.3068x over previous
//
#include <hip/hip_runtime.h>
#include <hip/hip_bf16.h>

typedef unsigned short u16;
typedef unsigned int u32;
typedef __attribute__((ext_vector_type(8))) short bf16x8;
typedef __attribute__((ext_vector_type(4))) float f32x4;

#define MFMA16(a, b, c) __builtin_amdgcn_mfma_f32_16x16x32_bf16((a), (b), (c), 0, 0, 0)

__device__ __forceinline__ u16 f2bf(float f) {
    u32 u;
    __builtin_memcpy(&u, &f, 4);
    u32 r = (u + 0x7FFFu + ((u >> 16) & 1u)) >> 16;  // RNE
    return (u16)r;
}

__device__ __forceinline__ u32 pk_bf16(float a, float b) {
    __hip_bfloat162 h = __float22bfloat162_rn(make_float2(a, b));  // v_cvt_pk_bf16_f32
    u32 r;
    __builtin_memcpy(&r, &h, 4);
    return r;
}

__device__ __forceinline__ void gload16(const void* g, void* l) {
    __builtin_amdgcn_global_load_lds((const __attribute__((address_space(1))) u32*)g,
                                     (__attribute__((address_space(3))) u32*)l, 16, 0, 0);
}

// fp32 -> bf16 bulk convert; each thread handles 8 floats.
__global__ __launch_bounds__(256) void cvt_bf16(const float* __restrict__ in, u16* __restrict__ out) {
    size_t i = ((size_t)blockIdx.x * 256 + threadIdx.x) * 8;
    f32x4 a = *(const f32x4*)(in + i);
    f32x4 b = *(const f32x4*)(in + i + 4);
    union {
        bf16x8 v;
        u16 s[8];
    } r;
    r.s[0] = f2bf(a[0]);
    r.s[1] = f2bf(a[1]);
    r.s[2] = f2bf(a[2]);
    r.s[3] = f2bf(a[3]);
    r.s[4] = f2bf(b[0]);
    r.s[5] = f2bf(b[1]);
    r.s[6] = f2bf(b[2]);
    r.s[7] = f2bf(b[3]);
    *(bf16x8*)(out + i) = r.v;
}

// out[C][R] = bf16(in[R][C])^T, 64x64 LDS tiles (fp32 in, bf16 out)
__global__ __launch_bounds__(256) void transpose_f32_bf16(const float* __restrict__ in,
                                                          u16* __restrict__ out, int R, int C) {
    __shared__ u16 t[64][65];
    const int c0 = blockIdx.x * 64, r0 = blockIdx.y * 64;
    const int tid = threadIdx.x;
#pragma unroll
    for (int i = 0; i < 16; ++i) {
        int idx = i * 256 + tid;
        int r = idx >> 6, c = idx & 63;
        t[r][c] = f2bf(in[(size_t)(r0 + r) * C + c0 + c]);
    }
    __syncthreads();
#pragma unroll
    for (int i = 0; i < 16; ++i) {
        int idx = i * 256 + tid;
        int cc = idx >> 6, rr = idx & 63;
        out[(size_t)(c0 + cc) * R + r0 + rr] = t[rr][cc];
    }
}

// Stage a ROWS x 64-element bf16 tile into linear LDS (row = 128 bytes = 8 chunks
// of 16B). Source chunk index is XOR-swizzled by (row&7); readers XOR the
// 16B-chunk index with (row&7). global_load_lds dest = wave-uniform base + lane*16.
template <int ROWS>
__device__ __forceinline__ void stage_tile(const u16* gbase, int stride_e, u16* lds, int tid) {
    const int wbase16 = (tid & ~63) * 8;
#pragma unroll
    for (int i = 0; i < ROWS / 32; ++i) {
        int chunk = i * 256 + tid;
        int r = chunk >> 3;
        int c = chunk & 7;
        int sc = c ^ (r & 7);
        const u16* src = gbase + (size_t)r * stride_e + sc * 8;
        u16* dst = lds + i * 2048 + wbase16;
        gload16(src, dst);
    }
}

// softmax scale folded into Q at the QKV epilogue: 1/sqrt(64) * log2(e)
#define QSCALE 0.1803368801111243f

// C = A[M,K] * Bt[N,K]^T + bias (bias fp32).
// split=1 (QKV): cols<1024 -> Q*QSCALE; cols<2048 -> Cb=[M][2048] bf16 (Q|K);
//                cols>=2048 (V) -> vt[bh*64+dh][2048] bf16.
// split=0: Cf[M][Cstride] fp32.
__global__ __launch_bounds__(256) void gemm_bt(const u16* __restrict__ A, const u16* __restrict__ Bt,
                                               const float* __restrict__ bias, u16* __restrict__ Cb,
                                               u16* __restrict__ vt, float* __restrict__ Cf, int M,
                                               int N, int K, int Cstride, int split) {
    __shared__ __align__(16) u16 As[128 * 64];
    __shared__ __align__(16) u16 Bs[128 * 64];
    const int tid = threadIdx.x;
    const int lane = tid & 63, wid = tid >> 6;
    const int wr = wid >> 1, wc = wid & 1;
    const int g = lane >> 4, l15 = lane & 15;
    const int m0 = blockIdx.y * 128, n0 = blockIdx.x * 128;

    f32x4 acc[4][4] = {};

    for (int k0 = 0; k0 < K; k0 += 64) {
        __syncthreads();
        stage_tile<128>(A + (size_t)m0 * K + k0, K, As, tid);
        stage_tile<128>(Bt + (size_t)n0 * K + k0, K, Bs, tid);
        __syncthreads();
        bf16x8 af[4][2], bf[4][2];
#pragma unroll
        for (int m = 0; m < 4; ++m) {
            int row = wr * 64 + m * 16 + l15;
#pragma unroll
            for (int t = 0; t < 2; ++t) {
                int off = row * 128 + (((t * 4 + g) ^ (row & 7)) * 16);
                af[m][t] = *(const bf16x8*)((const char*)As + off);
            }
        }
#pragma unroll
        for (int n = 0; n < 4; ++n) {
            int row = wc * 64 + n * 16 + l15;
#pragma unroll
            for (int t = 0; t < 2; ++t) {
                int off = row * 128 + (((t * 4 + g) ^ (row & 7)) * 16);
                bf[n][t] = *(const bf16x8*)((const char*)Bs + off);
            }
        }
#pragma unroll
        for (int m = 0; m < 4; ++m)
#pragma unroll
            for (int n = 0; n < 4; ++n) {
                acc[m][n] = MFMA16(af[m][0], bf[n][0], acc[m][n]);
                acc[m][n] = MFMA16(af[m][1], bf[n][1], acc[m][n]);
            }
    }

#pragma unroll
    for (int m = 0; m < 4; ++m) {
        int row0 = m0 + wr * 64 + m * 16 + g * 4;  // C row = (lane>>4)*4 + reg
#pragma unroll
        for (int n = 0; n < 4; ++n) {
            int col = n0 + wc * 64 + n * 16 + l15;  // C col = lane&15
            float bs = bias ? bias[col] : 0.0f;
            if (!split) {
#pragma unroll
                for (int rr = 0; rr < 4; ++rr)
                    Cf[(size_t)(row0 + rr) * Cstride + col] = acc[m][n][rr] + bs;
            } else {
                if (col < 2048) {
                    float scale = (col < 1024) ? QSCALE : 1.0f;
#pragma unroll
                    for (int rr = 0; rr < 4; ++rr)
                        Cb[(size_t)(row0 + rr) * 2048 + col] = f2bf((acc[m][n][rr] + bs) * scale);
                } else {
                    int e2 = col - 2048;
                    int h = e2 >> 6, dh = e2 & 63;
                    int b = row0 >> 11, s = row0 & 2047;
                    u16 tmp[4];
#pragma unroll
                    for (int rr = 0; rr < 4; ++rr) tmp[rr] = f2bf(acc[m][n][rr] + bs);
                    u32 lo = (u32)tmp[0] | ((u32)tmp[1] << 16);
                    u32 hi = (u32)tmp[2] | ((u32)tmp[3] << 16);
                    u32* dst = (u32*)&vt[((size_t)((b * 16 + h) * 64 + dh)) * 2048 + s];
                    dst[0] = lo;
                    dst[1] = hi;
                }
            }
        }
    }
}

// Flash attention, swapped-QK^T in-lane softmax (T12 pattern).
// qk = [8192][2048] bf16 (Q pre-scaled by QSCALE, cols 0..1023 | K cols 1024..2047),
// vt = [64bh][64d][2048s] bf16. Block: (qtile, bh). 4 waves x 16 q-rows.
// Swapped S^T = mfma(K_frag, Q_frag): lane (g,l15) holds S[kv=f*16+g*4+rr][q=l15]
// -> full 64-kv row slice of ONE q-row per lane-quad; softmax = lane-local + 2 shfl.
__global__ __launch_bounds__(256) void attn_fwd(const u16* __restrict__ qk, const u16* __restrict__ vt,
                                                u16* __restrict__ out) {
    __shared__ __align__(16) u16 Ks[64 * 64];
    __shared__ __align__(16) u16 Vs[64 * 64];
    __shared__ __align__(16) u16 Ps[4][16 * 72];  // per-wave P[q=16][kv=64], stride 72 elem
    const int tid = threadIdx.x;
    const int lane = tid & 63, w = tid >> 6;
    const int g = lane >> 4, l15 = lane & 15;
    const int bh = blockIdx.y, b = bh >> 4, h = bh & 15;
    const int q0 = blockIdx.x * 64 + w * 16;
    const size_t qrow = (size_t)b * 2048 + q0;

    bf16x8 qf[2];  // B-operand: col=q=l15, k-elems d = t*32+g*8..+7
#pragma unroll
    for (int t = 0; t < 2; ++t)
        qf[t] = *(const bf16x8*)&qk[(qrow + l15) * 2048 + h * 64 + t * 32 + g * 8];

    float m_r = -1e30f, l_r = 0.f;  // stats for q-row l15 (replicated over g)
    f32x4 acc_o[4] = {};

    const u16* kbase = qk + (size_t)b * 2048 * 2048 + 1024 + h * 64;
    const u16* vbase = vt + (size_t)bh * 64 * 2048;
    char* PsW = (char*)&Ps[w][0];

    for (int kv0 = 0; kv0 < 2048; kv0 += 64) {
        __syncthreads();
        stage_tile<64>(kbase + (size_t)kv0 * 2048, 2048, Ks, tid);
        stage_tile<64>(vbase + kv0, 2048, Vs, tid);
        __syncthreads();

        // S^T tile: sv[f][rr] = S[kv=f*16+g*4+rr][q=l15]  (Q pre-scaled)
        f32x4 sv[4];
        __builtin_amdgcn_s_setprio(1);
#pragma unroll
        for (int f = 0; f < 4; ++f) {
            int row = f * 16 + l15;
            int swz = row & 7;
            bf16x8 k0 = *(const bf16x8*)((const char*)Ks + row * 128 + ((g ^ swz) * 16));
            bf16x8 k1 = *(const bf16x8*)((const char*)Ks + row * 128 + (((4 + g) ^ swz) * 16));
            f32x4 s = {0.f, 0.f, 0.f, 0.f};
            s = MFMA16(k0, qf[0], s);
            s = MFMA16(k1, qf[1], s);
            sv[f] = s;
        }
        __builtin_amdgcn_s_setprio(0);

        // online softmax in exp2 domain, row = q = l15
        float mx = fmaxf(fmaxf(fmaxf(sv[0][0], sv[0][1]), fmaxf(sv[0][2], sv[0][3])),
                         fmaxf(fmaxf(sv[1][0], sv[1][1]), fmaxf(sv[1][2], sv[1][3])));
        mx = fmaxf(mx, fmaxf(fmaxf(fmaxf(sv[2][0], sv[2][1]), fmaxf(sv[2][2], sv[2][3])),
                             fmaxf(fmaxf(sv[3][0], sv[3][1]), fmaxf(sv[3][2], sv[3][3]))));
        mx = fmaxf(mx, __shfl_xor(mx, 16));
        mx = fmaxf(mx, __shfl_xor(mx, 32));
        float mn = fmaxf(m_r, mx);
        float alpha = __builtin_amdgcn_exp2f(m_r - mn);
        m_r = mn;
        float rsum = 0.f;
#pragma unroll
        for (int f = 0; f < 4; ++f)
#pragma unroll
            for (int rr = 0; rr < 4; ++rr) {
                float p = __builtin_amdgcn_exp2f(sv[f][rr] - mn);
                sv[f][rr] = p;
                rsum += p;
            }
        rsum += __shfl_xor(rsum, 16);
        rsum += __shfl_xor(rsum, 32);
        l_r = l_r * alpha + rsum;

        // P -> bf16 LDS: per f, 4 kv-consecutive values -> 2 cvt_pk + 1 b64 store
#pragma unroll
        for (int f = 0; f < 4; ++f) {
            uint2 pk;
            pk.x = pk_bf16(sv[f][0], sv[f][1]);
            pk.y = pk_bf16(sv[f][2], sv[f][3]);
            *(uint2*)(PsW + l15 * 144 + f * 32 + g * 8) = pk;
        }

        // rescale acc_o rows (row q = g*4+rr) by alpha of that row
        float ar[4];
#pragma unroll
        for (int rr = 0; rr < 4; ++rr) ar[rr] = __shfl(alpha, g * 4 + rr);
#pragma unroll
        for (int fo = 0; fo < 4; ++fo)
#pragma unroll
            for (int rr = 0; rr < 4; ++rr) acc_o[fo][rr] *= ar[rr];

        // PV: A = P (row=q=l15, k=kv), B = Vt (col=d, k=kv)
        bf16x8 pa[2];
#pragma unroll
        for (int t = 0; t < 2; ++t) pa[t] = *(const bf16x8*)(PsW + l15 * 144 + t * 64 + g * 16);

        __builtin_amdgcn_s_setprio(1);
#pragma unroll
        for (int fo = 0; fo < 4; ++fo) {
            int row = fo * 16 + l15;
            int swz = row & 7;
            bf16x8 v0 = *(const bf16x8*)((const char*)Vs + row * 128 + ((g ^ swz) * 16));
            bf16x8 v1 = *(const bf16x8*)((const char*)Vs + row * 128 + (((4 + g) ^ swz) * 16));
            acc_o[fo] = MFMA16(pa[0], v0, acc_o[fo]);
            acc_o[fo] = MFMA16(pa[1], v1, acc_o[fo]);
        }
        __builtin_amdgcn_s_setprio(0);
    }

    float lr[4];
#pragma unroll
    for (int rr = 0; rr < 4; ++rr) lr[rr] = __shfl(l_r, g * 4 + rr);
#pragma unroll
    for (int fo = 0; fo < 4; ++fo) {
        int col = h * 64 + fo * 16 + l15;
#pragma unroll
        for (int rr = 0; rr < 4; ++rr) {
            out[(qrow + g * 4 + rr) * 1024 + col] = f2bf(acc_o[fo][rr] / lr[rr]);
        }
    }
}

extern "C" void kernel_launch(void* const* d_in, const int* in_sizes, int n_in, void* d_out,
                              int out_size, void* d_ws, size_t ws_size, hipStream_t stream) {
    const float* x = (const float*)d_in[0];      // [4,2048,1024] fp32
    const float* w_qkv = (const float*)d_in[1];  // [1024,3072] fp32
    const float* b_qkv = (const float*)d_in[2];  // [3072] fp32
    const float* w_out = (const float*)d_in[3];  // [1024,1024] fp32
    const float* b_out = (const float*)d_in[4];  // [1024] fp32
    float* out = (float*)d_out;                  // [8192,1024] fp32

    u16* ws = (u16*)d_ws;
    u16* xbf = ws;                                // 8192*1024
    u16* WqkvT = xbf + (size_t)8192 * 1024;       // 3072*1024
    u16* WoutT = WqkvT + (size_t)3072 * 1024;     // 1024*1024
    u16* qkbuf = WoutT + (size_t)1024 * 1024;     // 8192*2048 (Q|K)
    u16* vtbuf = qkbuf + (size_t)8192 * 2048;     // 64*64*2048 (V transposed per head)
    u16* attnb = vtbuf + (size_t)64 * 64 * 2048;  // 8192*1024
    // total ws: 92,274,688 bytes

    cvt_bf16<<<4096, 256, 0, stream>>>(x, xbf);
    transpose_f32_bf16<<<dim3(48, 16), 256, 0, stream>>>(w_qkv, WqkvT, 1024, 3072);
    transpose_f32_bf16<<<dim3(16, 16), 256, 0, stream>>>(w_out, WoutT, 1024, 1024);

    // QKV projection: [8192,1024] x [1024,3072] + b_qkv -> qkbuf + vtbuf (Q pre-scaled)
    gemm_bt<<<dim3(24, 64), 256, 0, stream>>>(xbf, WqkvT, b_qkv, qkbuf, vtbuf, nullptr, 8192, 3072,
                                              1024, 2048, 1);

    // attention: grid (qtile=32, bh=64)
    attn_fwd<<<dim3(32, 64), 256, 0, stream>>>(qkbuf, vtbuf, attnb);

    // output projection: [8192,1024] x [1024,1024] + b_out -> d_out (fp32)
    gemm_bt<<<dim3(8, 64), 256, 0, stream>>>(attnb, WoutT, b_out, nullptr, nullptr, out, 8192, 1024,
                                             1024, 1024, 0);
}

// Round 4
// 222.299 us; speedup vs baseline: 1.4964x; 1.1451x over previous
//
#include <hip/hip_runtime.h>
#include <hip/hip_bf16.h>

typedef unsigned short u16;
typedef unsigned int u32;
typedef __attribute__((ext_vector_type(8))) short bf16x8;
typedef __attribute__((ext_vector_type(4))) float f32x4;
typedef __attribute__((ext_vector_type(16))) float f32x16;

#define MFMA16(a, b, c) __builtin_amdgcn_mfma_f32_16x16x32_bf16((a), (b), (c), 0, 0, 0)
#define MFMA32(a, b, c) __builtin_amdgcn_mfma_f32_32x32x16_bf16((a), (b), (c), 0, 0, 0)

__device__ __forceinline__ u16 f2bf(float f) {
    u32 u;
    __builtin_memcpy(&u, &f, 4);
    u32 r = (u + 0x7FFFu + ((u >> 16) & 1u)) >> 16;  // RNE
    return (u16)r;
}

__device__ __forceinline__ u32 pk_bf16(float a, float b) {
    __hip_bfloat162 h = __float22bfloat162_rn(make_float2(a, b));  // v_cvt_pk_bf16_f32
    u32 r;
    __builtin_memcpy(&r, &h, 4);
    return r;
}

__device__ __forceinline__ void gload16(const void* g, void* l) {
    __builtin_amdgcn_global_load_lds((const __attribute__((address_space(1))) u32*)g,
                                     (__attribute__((address_space(3))) u32*)l, 16, 0, 0);
}

// fp32 -> bf16 bulk convert; each thread handles 8 floats.
__global__ __launch_bounds__(256) void cvt_bf16(const float* __restrict__ in, u16* __restrict__ out) {
    size_t i = ((size_t)blockIdx.x * 256 + threadIdx.x) * 8;
    f32x4 a = *(const f32x4*)(in + i);
    f32x4 b = *(const f32x4*)(in + i + 4);
    union {
        bf16x8 v;
        u16 s[8];
    } r;
    r.s[0] = f2bf(a[0]);
    r.s[1] = f2bf(a[1]);
    r.s[2] = f2bf(a[2]);
    r.s[3] = f2bf(a[3]);
    r.s[4] = f2bf(b[0]);
    r.s[5] = f2bf(b[1]);
    r.s[6] = f2bf(b[2]);
    r.s[7] = f2bf(b[3]);
    *(bf16x8*)(out + i) = r.v;
}

// out[C][R] = bf16(in[R][C])^T, 64x64 LDS tiles (fp32 in, bf16 out)
__global__ __launch_bounds__(256) void transpose_f32_bf16(const float* __restrict__ in,
                                                          u16* __restrict__ out, int R, int C) {
    __shared__ u16 t[64][65];
    const int c0 = blockIdx.x * 64, r0 = blockIdx.y * 64;
    const int tid = threadIdx.x;
#pragma unroll
    for (int i = 0; i < 16; ++i) {
        int idx = i * 256 + tid;
        int r = idx >> 6, c = idx & 63;
        t[r][c] = f2bf(in[(size_t)(r0 + r) * C + c0 + c]);
    }
    __syncthreads();
#pragma unroll
    for (int i = 0; i < 16; ++i) {
        int idx = i * 256 + tid;
        int cc = idx >> 6, rr = idx & 63;
        out[(size_t)(c0 + cc) * R + r0 + rr] = t[rr][cc];
    }
}

// Stage a ROWS x 64-element bf16 tile into linear LDS (row = 128 bytes = 8 chunks
// of 16B). Source chunk index is XOR-swizzled by (row&7); readers XOR the
// 16B-chunk index with (row&7). global_load_lds dest = wave-uniform base + lane*16.
template <int ROWS>
__device__ __forceinline__ void stage_tile(const u16* gbase, int stride_e, u16* lds, int tid) {
    const int wbase16 = (tid & ~63) * 8;
#pragma unroll
    for (int i = 0; i < ROWS / 32; ++i) {
        int chunk = i * 256 + tid;
        int r = chunk >> 3;
        int c = chunk & 7;
        int sc = c ^ (r & 7);
        const u16* src = gbase + (size_t)r * stride_e + sc * 8;
        u16* dst = lds + i * 2048 + wbase16;
        gload16(src, dst);
    }
}

// softmax scale folded into Q at the QKV epilogue: 1/sqrt(64) * log2(e)
#define QSCALE 0.1803368801111243f

// C = A[M,K] * Bt[N,K]^T + bias (bias fp32).
// split=1 (QKV): cols<1024 -> Q*QSCALE; cols<2048 -> Cb=[M][2048] bf16 (Q|K);
//                cols>=2048 (V) -> vt[bh*64+dh][2048] bf16.
// split=0: Cf[M][Cstride] fp32.
__global__ __launch_bounds__(256) void gemm_bt(const u16* __restrict__ A, const u16* __restrict__ Bt,
                                               const float* __restrict__ bias, u16* __restrict__ Cb,
                                               u16* __restrict__ vt, float* __restrict__ Cf, int M,
                                               int N, int K, int Cstride, int split) {
    __shared__ __align__(16) u16 As[128 * 64];
    __shared__ __align__(16) u16 Bs[128 * 64];
    const int tid = threadIdx.x;
    const int lane = tid & 63, wid = tid >> 6;
    const int wr = wid >> 1, wc = wid & 1;
    const int g = lane >> 4, l15 = lane & 15;
    const int m0 = blockIdx.y * 128, n0 = blockIdx.x * 128;

    f32x4 acc[4][4] = {};

    for (int k0 = 0; k0 < K; k0 += 64) {
        __syncthreads();
        stage_tile<128>(A + (size_t)m0 * K + k0, K, As, tid);
        stage_tile<128>(Bt + (size_t)n0 * K + k0, K, Bs, tid);
        __syncthreads();
        bf16x8 af[4][2], bf[4][2];
#pragma unroll
        for (int m = 0; m < 4; ++m) {
            int row = wr * 64 + m * 16 + l15;
#pragma unroll
            for (int t = 0; t < 2; ++t) {
                int off = row * 128 + (((t * 4 + g) ^ (row & 7)) * 16);
                af[m][t] = *(const bf16x8*)((const char*)As + off);
            }
        }
#pragma unroll
        for (int n = 0; n < 4; ++n) {
            int row = wc * 64 + n * 16 + l15;
#pragma unroll
            for (int t = 0; t < 2; ++t) {
                int off = row * 128 + (((t * 4 + g) ^ (row & 7)) * 16);
                bf[n][t] = *(const bf16x8*)((const char*)Bs + off);
            }
        }
#pragma unroll
        for (int m = 0; m < 4; ++m)
#pragma unroll
            for (int n = 0; n < 4; ++n) {
                acc[m][n] = MFMA16(af[m][0], bf[n][0], acc[m][n]);
                acc[m][n] = MFMA16(af[m][1], bf[n][1], acc[m][n]);
            }
    }

#pragma unroll
    for (int m = 0; m < 4; ++m) {
        int row0 = m0 + wr * 64 + m * 16 + g * 4;  // C row = (lane>>4)*4 + reg
#pragma unroll
        for (int n = 0; n < 4; ++n) {
            int col = n0 + wc * 64 + n * 16 + l15;  // C col = lane&15
            float bs = bias ? bias[col] : 0.0f;
            if (!split) {
#pragma unroll
                for (int rr = 0; rr < 4; ++rr)
                    Cf[(size_t)(row0 + rr) * Cstride + col] = acc[m][n][rr] + bs;
            } else {
                if (col < 2048) {
                    float scale = (col < 1024) ? QSCALE : 1.0f;
#pragma unroll
                    for (int rr = 0; rr < 4; ++rr)
                        Cb[(size_t)(row0 + rr) * 2048 + col] = f2bf((acc[m][n][rr] + bs) * scale);
                } else {
                    int e2 = col - 2048;
                    int h = e2 >> 6, dh = e2 & 63;
                    int b = row0 >> 11, s = row0 & 2047;
                    u16 tmp[4];
#pragma unroll
                    for (int rr = 0; rr < 4; ++rr) tmp[rr] = f2bf(acc[m][n][rr] + bs);
                    u32 lo = (u32)tmp[0] | ((u32)tmp[1] << 16);
                    u32 hi = (u32)tmp[2] | ((u32)tmp[3] << 16);
                    u32* dst = (u32*)&vt[((size_t)((b * 16 + h) * 64 + dh)) * 2048 + s];
                    dst[0] = lo;
                    dst[1] = hi;
                }
            }
        }
    }
}

// Flash attention, 32x32 MFMA, in-register P via cvt_pk + permlane32_swap.
// qk = [8192][2048] bf16 (Q pre-scaled, cols 0..1023 | K cols 1024..2047),
// vt = [64bh][64d][2048s] bf16. Block: (qtile of 128, bh). 4 waves x 32 q-rows.
// Swapped S^T = mfma32(K,Q): lane(hi,l31) holds S[kv=(reg&3)+8*(reg>>2)+4*hi][q=l31].
__global__ __launch_bounds__(256, 4) void attn_fwd(const u16* __restrict__ qk,
                                                   const u16* __restrict__ vt,
                                                   u16* __restrict__ out) {
    __shared__ __align__(16) u16 Ks[2][64 * 64];
    __shared__ __align__(16) u16 Vs[2][64 * 64];
    const int tid = threadIdx.x;
    const int lane = tid & 63, w = tid >> 6;
    const int hi = lane >> 5, l31 = lane & 31;
    const int bh = blockIdx.y, b = bh >> 4, h = bh & 15;
    const int q0w = blockIdx.x * 128 + w * 32;
    const size_t qrowbase = (size_t)b * 2048 + q0w;

    bf16x8 qf[4];  // B-operand: col=q=l31, k-elems d = c*16 + hi*8 + j
#pragma unroll
    for (int c = 0; c < 4; ++c)
        qf[c] = *(const bf16x8*)&qk[(qrowbase + l31) * 2048 + h * 64 + c * 16 + hi * 8];

    float m_r = -1e30f, l_r = 0.f;  // per q=l31 (replicated over hi)
    f32x16 acc[2] = {};

    const u16* kbase = qk + (size_t)b * 2048 * 2048 + 1024 + h * 64;
    const u16* vbase = vt + (size_t)bh * 64 * 2048;

    stage_tile<64>(kbase, 2048, &Ks[0][0], tid);
    stage_tile<64>(vbase, 2048, &Vs[0][0], tid);
    __syncthreads();

    int cur = 0;
    for (int kv0 = 0; kv0 < 2048; kv0 += 64) {
        if (kv0 + 64 < 2048) {
            stage_tile<64>(kbase + (size_t)(kv0 + 64) * 2048, 2048, &Ks[cur ^ 1][0], tid);
            stage_tile<64>(vbase + (kv0 + 64), 2048, &Vs[cur ^ 1][0], tid);
        }
        const char* ks = (const char*)&Ks[cur][0];
        const char* vs = (const char*)&Vs[cur][0];

#pragma unroll
        for (int kb = 0; kb < 2; ++kb) {
            // S^T for kv32-block kb: rows kv, cols q
            f32x16 s = {};
            const int arow = kb * 32 + l31;
            const int aswz = l31 & 7;
            __builtin_amdgcn_s_setprio(1);
#pragma unroll
            for (int c = 0; c < 4; ++c) {
                bf16x8 kf = *(const bf16x8*)(ks + arow * 128 + (((2 * c + hi) ^ aswz) * 16));
                s = MFMA32(kf, qf[c], s);
            }
            __builtin_amdgcn_s_setprio(0);

            // online softmax (exp2 domain), defer-max THR=8
            float pmax = fmaxf(fmaxf(s[0], s[1]), s[2]);
            pmax = fmaxf(fmaxf(pmax, s[3]), s[4]);
            pmax = fmaxf(fmaxf(pmax, s[5]), s[6]);
            pmax = fmaxf(fmaxf(pmax, s[7]), s[8]);
            pmax = fmaxf(fmaxf(pmax, s[9]), s[10]);
            pmax = fmaxf(fmaxf(pmax, s[11]), s[12]);
            pmax = fmaxf(fmaxf(pmax, s[13]), s[14]);
            pmax = fmaxf(pmax, s[15]);
            pmax = fmaxf(pmax, __shfl_xor(pmax, 32));
            if (__any(pmax > m_r + 8.0f)) {
                float mn = fmaxf(m_r, pmax);
                float alpha = __builtin_amdgcn_exp2f(m_r - mn);
                m_r = mn;
                l_r *= alpha;
                float ar[16];
#pragma unroll
                for (int r = 0; r < 16; ++r)
                    ar[r] = __shfl(alpha, (r & 3) + 8 * (r >> 2) + 4 * hi);
#pragma unroll
                for (int d = 0; d < 2; ++d)
#pragma unroll
                    for (int r = 0; r < 16; ++r) acc[d][r] *= ar[r];
            }

            float rsum = 0.f;
            u32 pk[8];
#pragma unroll
            for (int j = 0; j < 8; ++j) {
                float p0 = __builtin_amdgcn_exp2f(s[2 * j] - m_r);
                float p1 = __builtin_amdgcn_exp2f(s[2 * j + 1] - m_r);
                rsum += p0 + p1;
                pk[j] = pk_bf16(p0, p1);
            }
            rsum += __shfl_xor(rsum, 32);
            l_r += rsum;

            // Assemble PV A-frags in-register: word pattern {own-lo, other-half}
            auto s02 = __builtin_amdgcn_permlane32_swap(pk[0], pk[2], false, false);
            auto s13 = __builtin_amdgcn_permlane32_swap(pk[1], pk[3], false, false);
            auto s46 = __builtin_amdgcn_permlane32_swap(pk[4], pk[6], false, false);
            auto s57 = __builtin_amdgcn_permlane32_swap(pk[5], pk[7], false, false);
            union {
                bf16x8 v;
                u32 u[4];
            } a0, a1;
            a0.u[0] = s02[0];
            a0.u[1] = s13[0];
            a0.u[2] = s02[1];
            a0.u[3] = s13[1];
            a1.u[0] = s46[0];
            a1.u[1] = s57[0];
            a1.u[2] = s46[1];
            a1.u[3] = s57[1];

            // PV: A = P[q x kv16], B = V[kv16 x d] from Vs[d][kv]
            __builtin_amdgcn_s_setprio(1);
#pragma unroll
            for (int d = 0; d < 2; ++d) {
                const int vrow = d * 32 + l31;
                const int vswz = l31 & 7;
                bf16x8 v0 = *(const bf16x8*)(vs + vrow * 128 + (((4 * kb + hi) ^ vswz) * 16));
                bf16x8 v1 = *(const bf16x8*)(vs + vrow * 128 + (((4 * kb + 2 + hi) ^ vswz) * 16));
                acc[d] = MFMA32(a0.v, v0, acc[d]);
                acc[d] = MFMA32(a1.v, v1, acc[d]);
            }
            __builtin_amdgcn_s_setprio(0);
        }
        __syncthreads();
        cur ^= 1;
    }

    float lr[16];
#pragma unroll
    for (int r = 0; r < 16; ++r) lr[r] = __shfl(l_r, (r & 3) + 8 * (r >> 2) + 4 * hi);
#pragma unroll
    for (int d = 0; d < 2; ++d)
#pragma unroll
        for (int r = 0; r < 16; ++r) {
            int q = (r & 3) + 8 * (r >> 2) + 4 * hi;
            out[(qrowbase + q) * 1024 + h * 64 + d * 32 + l31] = f2bf(acc[d][r] / lr[r]);
        }
}

extern "C" void kernel_launch(void* const* d_in, const int* in_sizes, int n_in, void* d_out,
                              int out_size, void* d_ws, size_t ws_size, hipStream_t stream) {
    const float* x = (const float*)d_in[0];      // [4,2048,1024] fp32
    const float* w_qkv = (const float*)d_in[1];  // [1024,3072] fp32
    const float* b_qkv = (const float*)d_in[2];  // [3072] fp32
    const float* w_out = (const float*)d_in[3];  // [1024,1024] fp32
    const float* b_out = (const float*)d_in[4];  // [1024] fp32
    float* out = (float*)d_out;                  // [8192,1024] fp32

    u16* ws = (u16*)d_ws;
    u16* xbf = ws;                                // 8192*1024
    u16* WqkvT = xbf + (size_t)8192 * 1024;       // 3072*1024
    u16* WoutT = WqkvT + (size_t)3072 * 1024;     // 1024*1024
    u16* qkbuf = WoutT + (size_t)1024 * 1024;     // 8192*2048 (Q|K)
    u16* vtbuf = qkbuf + (size_t)8192 * 2048;     // 64*64*2048 (V transposed per head)
    u16* attnb = vtbuf + (size_t)64 * 64 * 2048;  // 8192*1024
    // total ws: 92,274,688 bytes

    cvt_bf16<<<4096, 256, 0, stream>>>(x, xbf);
    transpose_f32_bf16<<<dim3(48, 16), 256, 0, stream>>>(w_qkv, WqkvT, 1024, 3072);
    transpose_f32_bf16<<<dim3(16, 16), 256, 0, stream>>>(w_out, WoutT, 1024, 1024);

    // QKV projection: [8192,1024] x [1024,3072] + b_qkv -> qkbuf + vtbuf (Q pre-scaled)
    gemm_bt<<<dim3(24, 64), 256, 0, stream>>>(xbf, WqkvT, b_qkv, qkbuf, vtbuf, nullptr, 8192, 3072,
                                              1024, 2048, 1);

    // attention: grid (qtile=16, bh=64), 128 q-rows per block
    attn_fwd<<<dim3(16, 64), 256, 0, stream>>>(qkbuf, vtbuf, attnb);

    // output projection: [8192,1024] x [1024,1024] + b_out -> d_out (fp32)
    gemm_bt<<<dim3(8, 64), 256, 0, stream>>>(attnb, WoutT, b_out, nullptr, nullptr, out, 8192, 1024,
                                             1024, 1024, 0);
}